// Round 15
// baseline (116.191 us; speedup 1.0000x reference)
//
#include <hip/hip_runtime.h>

#define NROWS 2048
#define MCOLS 2048

// ---- d_ws layout (float offsets); rows padded to stride 20 ----
#define OFF_AF 0
#define OFF_AS (OFF_AF + NROWS * 20)
#define OFF_BF (OFF_AS + NROWS * 20)
#define OFF_BS (OFF_BF + NROWS * 20)
#define OFF_WP (OFF_BS + NROWS * 20)
#define OFF_CF (OFF_WP + 512)
#define OFF_CS (OFF_CF + NROWS)
#define OFF_LISTS (OFF_CS + NROWS)
#define LF_CAP ((size_t)NROWS * MCOLS)

#define WP_W1 0
#define WP_B1 162
#define WP_W2 171
#define WP_B2 225
#define WP_W3 231
#define WP_B3 249
#define WP_SOLID 252

// 2*log2(e): folded into A/B rows and W1/b1/W2/b2 at prep (R14, +12%).
#define TANH_K 2.8853900817779268f

__device__ __forceinline__ float tanh_pre(float x) {
    float t = __builtin_amdgcn_exp2f(x);
    return 1.0f - 2.0f * __builtin_amdgcn_rcpf(1.0f + t);
}

// ---------- champion eval (R11 + R14): scalar + layer-ILP fences ----------
__device__ __forceinline__ void eval_regs_ilp(float4 P0, float4 P1, float4 P2,
                                              float4 P3, float2 P4,
                                              const float* __restrict__ Bq,
                                              const float* __restrict__ W,
                                              float& p0, float& p1, float& p2) {
    float h[18];
    h[0]  = tanh_pre(P0.x + Bq[0]);  h[1]  = tanh_pre(P0.y + Bq[1]);
    h[2]  = tanh_pre(P0.z + Bq[2]);  h[3]  = tanh_pre(P0.w + Bq[3]);
    h[4]  = tanh_pre(P1.x + Bq[4]);  h[5]  = tanh_pre(P1.y + Bq[5]);
    h[6]  = tanh_pre(P1.z + Bq[6]);  h[7]  = tanh_pre(P1.w + Bq[7]);
    h[8]  = tanh_pre(P2.x + Bq[8]);  h[9]  = tanh_pre(P2.y + Bq[9]);
    h[10] = tanh_pre(P2.z + Bq[10]); h[11] = tanh_pre(P2.w + Bq[11]);
    h[12] = tanh_pre(P3.x + Bq[12]); h[13] = tanh_pre(P3.y + Bq[13]);
    h[14] = tanh_pre(P3.z + Bq[14]); h[15] = tanh_pre(P3.w + Bq[15]);
    h[16] = tanh_pre(P4.x + Bq[16]); h[17] = tanh_pre(P4.y + Bq[17]);
    asm volatile("" : "+v"(h[0]), "+v"(h[1]), "+v"(h[2]), "+v"(h[3]),
                      "+v"(h[4]), "+v"(h[5]), "+v"(h[6]), "+v"(h[7]),
                      "+v"(h[8]), "+v"(h[9]), "+v"(h[10]), "+v"(h[11]),
                      "+v"(h[12]), "+v"(h[13]), "+v"(h[14]), "+v"(h[15]),
                      "+v"(h[16]), "+v"(h[17]));
    float g[9];
#pragma unroll
    for (int o = 0; o < 9; ++o) g[o] = W[WP_B1 + o];
#pragma unroll
    for (int j = 0; j < 18; ++j) {
        const float a = h[j];
#pragma unroll
        for (int o = 0; o < 9; ++o) g[o] += a * W[WP_W1 + j * 9 + o];
    }
#pragma unroll
    for (int o = 0; o < 9; ++o) g[o] = tanh_pre(g[o]);
    asm volatile("" : "+v"(g[0]), "+v"(g[1]), "+v"(g[2]), "+v"(g[3]),
                      "+v"(g[4]), "+v"(g[5]), "+v"(g[6]), "+v"(g[7]),
                      "+v"(g[8]));
    float q[6];
#pragma unroll
    for (int o = 0; o < 6; ++o) q[o] = W[WP_B2 + o];
#pragma unroll
    for (int j = 0; j < 9; ++j) {
        const float a = g[j];
#pragma unroll
        for (int o = 0; o < 6; ++o) q[o] += a * W[WP_W2 + j * 6 + o];
    }
#pragma unroll
    for (int o = 0; o < 6; ++o) q[o] = tanh_pre(q[o]);
    asm volatile("" : "+v"(q[0]), "+v"(q[1]), "+v"(q[2]), "+v"(q[3]),
                      "+v"(q[4]), "+v"(q[5]));
    float o0 = W[WP_B3 + 0], o1 = W[WP_B3 + 1], o2 = W[WP_B3 + 2];
#pragma unroll
    for (int j = 0; j < 6; ++j) {
        const float a = q[j];
        o0 += a * W[WP_W3 + j * 3 + 0];
        o1 += a * W[WP_W3 + j * 3 + 1];
        o2 += a * W[WP_W3 + j * 3 + 2];
    }
    p0 += o0; p1 += o1; p2 += o2;
}

// ---------- experiment eval: TWO independent scalar evals interleaved ----------
// Unlike R12's pk-packing (which the compiler re-serialized, VGPR=36), these are
// two separate scalar streams with fences holding ALL 36/18/12 activations live;
// each weight s_load feeds 2 FMAs.
__device__ __forceinline__ void eval2_regs_ilp(
        float4 X0, float4 X1, float4 X2, float4 X3, float2 X4,
        float4 Y0, float4 Y1, float4 Y2, float4 Y3, float2 Y4,
        const float* __restrict__ Bq, const float* __restrict__ W,
        float& p0, float& p1, float& p2) {
    float hA[18], hB[18];
    hA[0]  = tanh_pre(X0.x + Bq[0]);  hB[0]  = tanh_pre(Y0.x + Bq[0]);
    hA[1]  = tanh_pre(X0.y + Bq[1]);  hB[1]  = tanh_pre(Y0.y + Bq[1]);
    hA[2]  = tanh_pre(X0.z + Bq[2]);  hB[2]  = tanh_pre(Y0.z + Bq[2]);
    hA[3]  = tanh_pre(X0.w + Bq[3]);  hB[3]  = tanh_pre(Y0.w + Bq[3]);
    hA[4]  = tanh_pre(X1.x + Bq[4]);  hB[4]  = tanh_pre(Y1.x + Bq[4]);
    hA[5]  = tanh_pre(X1.y + Bq[5]);  hB[5]  = tanh_pre(Y1.y + Bq[5]);
    hA[6]  = tanh_pre(X1.z + Bq[6]);  hB[6]  = tanh_pre(Y1.z + Bq[6]);
    hA[7]  = tanh_pre(X1.w + Bq[7]);  hB[7]  = tanh_pre(Y1.w + Bq[7]);
    hA[8]  = tanh_pre(X2.x + Bq[8]);  hB[8]  = tanh_pre(Y2.x + Bq[8]);
    hA[9]  = tanh_pre(X2.y + Bq[9]);  hB[9]  = tanh_pre(Y2.y + Bq[9]);
    hA[10] = tanh_pre(X2.z + Bq[10]); hB[10] = tanh_pre(Y2.z + Bq[10]);
    hA[11] = tanh_pre(X2.w + Bq[11]); hB[11] = tanh_pre(Y2.w + Bq[11]);
    hA[12] = tanh_pre(X3.x + Bq[12]); hB[12] = tanh_pre(Y3.x + Bq[12]);
    hA[13] = tanh_pre(X3.y + Bq[13]); hB[13] = tanh_pre(Y3.y + Bq[13]);
    hA[14] = tanh_pre(X3.z + Bq[14]); hB[14] = tanh_pre(Y3.z + Bq[14]);
    hA[15] = tanh_pre(X3.w + Bq[15]); hB[15] = tanh_pre(Y3.w + Bq[15]);
    hA[16] = tanh_pre(X4.x + Bq[16]); hB[16] = tanh_pre(Y4.x + Bq[16]);
    hA[17] = tanh_pre(X4.y + Bq[17]); hB[17] = tanh_pre(Y4.y + Bq[17]);
    asm volatile("" : "+v"(hA[0]), "+v"(hA[1]), "+v"(hA[2]), "+v"(hA[3]),
                      "+v"(hA[4]), "+v"(hA[5]), "+v"(hA[6]), "+v"(hA[7]),
                      "+v"(hA[8]), "+v"(hA[9]), "+v"(hA[10]), "+v"(hA[11]),
                      "+v"(hA[12]), "+v"(hA[13]), "+v"(hA[14]), "+v"(hA[15]),
                      "+v"(hA[16]), "+v"(hA[17]));
    asm volatile("" : "+v"(hB[0]), "+v"(hB[1]), "+v"(hB[2]), "+v"(hB[3]),
                      "+v"(hB[4]), "+v"(hB[5]), "+v"(hB[6]), "+v"(hB[7]),
                      "+v"(hB[8]), "+v"(hB[9]), "+v"(hB[10]), "+v"(hB[11]),
                      "+v"(hB[12]), "+v"(hB[13]), "+v"(hB[14]), "+v"(hB[15]),
                      "+v"(hB[16]), "+v"(hB[17]));
    float gA[9], gB[9];
#pragma unroll
    for (int o = 0; o < 9; ++o) { float b = W[WP_B1 + o]; gA[o] = b; gB[o] = b; }
#pragma unroll
    for (int j = 0; j < 18; ++j) {
        const float a = hA[j], b = hB[j];
#pragma unroll
        for (int o = 0; o < 9; ++o) {
            const float w = W[WP_W1 + j * 9 + o];
            gA[o] += a * w; gB[o] += b * w;
        }
    }
#pragma unroll
    for (int o = 0; o < 9; ++o) { gA[o] = tanh_pre(gA[o]); gB[o] = tanh_pre(gB[o]); }
    asm volatile("" : "+v"(gA[0]), "+v"(gA[1]), "+v"(gA[2]), "+v"(gA[3]),
                      "+v"(gA[4]), "+v"(gA[5]), "+v"(gA[6]), "+v"(gA[7]),
                      "+v"(gA[8]));
    asm volatile("" : "+v"(gB[0]), "+v"(gB[1]), "+v"(gB[2]), "+v"(gB[3]),
                      "+v"(gB[4]), "+v"(gB[5]), "+v"(gB[6]), "+v"(gB[7]),
                      "+v"(gB[8]));
    float qA[6], qB[6];
#pragma unroll
    for (int o = 0; o < 6; ++o) { float b = W[WP_B2 + o]; qA[o] = b; qB[o] = b; }
#pragma unroll
    for (int j = 0; j < 9; ++j) {
        const float a = gA[j], b = gB[j];
#pragma unroll
        for (int o = 0; o < 6; ++o) {
            const float w = W[WP_W2 + j * 6 + o];
            qA[o] += a * w; qB[o] += b * w;
        }
    }
#pragma unroll
    for (int o = 0; o < 6; ++o) { qA[o] = tanh_pre(qA[o]); qB[o] = tanh_pre(qB[o]); }
    asm volatile("" : "+v"(qA[0]), "+v"(qA[1]), "+v"(qA[2]), "+v"(qA[3]),
                      "+v"(qA[4]), "+v"(qA[5]));
    asm volatile("" : "+v"(qB[0]), "+v"(qB[1]), "+v"(qB[2]), "+v"(qB[3]),
                      "+v"(qB[4]), "+v"(qB[5]));
    float oA0 = W[WP_B3 + 0], oA1 = W[WP_B3 + 1], oA2 = W[WP_B3 + 2];
    float oB0 = oA0, oB1 = oA1, oB2 = oA2;
#pragma unroll
    for (int j = 0; j < 6; ++j) {
        const float a = qA[j], b = qB[j];
        const float w0 = W[WP_W3 + j * 3 + 0];
        const float w1 = W[WP_W3 + j * 3 + 1];
        const float w2 = W[WP_W3 + j * 3 + 2];
        oA0 += a * w0; oA1 += a * w1; oA2 += a * w2;
        oB0 += b * w0; oB1 += b * w1; oB2 += b * w2;
    }
    p0 += oA0 + oB0; p1 += oA1 + oB1; p2 += oA2 + oB2;
}

__device__ __forceinline__ void eval_single_at(const float* __restrict__ A, int m,
                                               const float* __restrict__ Bq,
                                               const float* __restrict__ W,
                                               float& p0, float& p1, float& p2) {
    const float* r = A + m * 20;
    eval_regs_ilp(*(const float4*)(r), *(const float4*)(r + 4),
                  *(const float4*)(r + 8), *(const float4*)(r + 12),
                  *(const float2*)(r + 16), Bq, W, p0, p1, p2);
}

// champion loop: scalar ILP eval + 2-deep register prefetch.
__device__ __forceinline__ void row_loop_ilp(const float* __restrict__ A,
                                             const unsigned short* __restrict__ lst,
                                             int cnt,
                                             const float* __restrict__ Bq,
                                             const float* __restrict__ W,
                                             int tid,
                                             float& p0, float& p1, float& p2) {
    int i = tid;
    if (i >= cnt) return;
    const float* r = A + (int)lst[i] * 20;
    float4 P0 = *(const float4*)(r);
    float4 P1 = *(const float4*)(r + 4);
    float4 P2 = *(const float4*)(r + 8);
    float4 P3 = *(const float4*)(r + 12);
    float2 P4 = *(const float2*)(r + 16);
    for (;;) {
        const int inext = i + 256;
        const bool more = inext < cnt;
        const float* rn = A + (int)lst[more ? inext : i] * 20;
        const float4 N0 = *(const float4*)(rn);
        const float4 N1 = *(const float4*)(rn + 4);
        const float4 N2 = *(const float4*)(rn + 8);
        const float4 N3 = *(const float4*)(rn + 12);
        const float2 N4 = *(const float2*)(rn + 16);
        eval_regs_ilp(P0, P1, P2, P3, P4, Bq, W, p0, p1, p2);
        if (!more) break;
        P0 = N0; P1 = N1; P2 = N2; P3 = N3; P4 = N4;
        i = inext;
    }
}

// experiment loop: dual-eval (i, i+256) per iteration, stride 512,
// 2-deep prefetch of the next PAIR; single-eval tail.
__device__ __forceinline__ void row_loop_x2(const float* __restrict__ A,
                                            const unsigned short* __restrict__ lst,
                                            int cnt,
                                            const float* __restrict__ Bq,
                                            const float* __restrict__ W,
                                            int tid,
                                            float& p0, float& p1, float& p2) {
    int i = tid;
    if (i + 256 < cnt) {
        const float* r0 = A + (int)lst[i] * 20;
        const float* r1 = A + (int)lst[i + 256] * 20;
        float4 X0 = *(const float4*)(r0);
        float4 X1 = *(const float4*)(r0 + 4);
        float4 X2 = *(const float4*)(r0 + 8);
        float4 X3 = *(const float4*)(r0 + 12);
        float2 X4 = *(const float2*)(r0 + 16);
        float4 Y0 = *(const float4*)(r1);
        float4 Y1 = *(const float4*)(r1 + 4);
        float4 Y2 = *(const float4*)(r1 + 8);
        float4 Y3 = *(const float4*)(r1 + 12);
        float2 Y4 = *(const float2*)(r1 + 16);
        for (;;) {
            const int inext = i + 512;
            const bool more = inext + 256 < cnt;
            const float* n0 = A + (int)lst[more ? inext : i] * 20;
            const float* n1 = A + (int)lst[more ? (inext + 256) : i] * 20;
            const float4 NX0 = *(const float4*)(n0);
            const float4 NX1 = *(const float4*)(n0 + 4);
            const float4 NX2 = *(const float4*)(n0 + 8);
            const float4 NX3 = *(const float4*)(n0 + 12);
            const float2 NX4 = *(const float2*)(n0 + 16);
            const float4 NY0 = *(const float4*)(n1);
            const float4 NY1 = *(const float4*)(n1 + 4);
            const float4 NY2 = *(const float4*)(n1 + 8);
            const float4 NY3 = *(const float4*)(n1 + 12);
            const float2 NY4 = *(const float2*)(n1 + 16);
            eval2_regs_ilp(X0, X1, X2, X3, X4, Y0, Y1, Y2, Y3, Y4,
                           Bq, W, p0, p1, p2);
            if (!more) { i = inext; break; }
            X0 = NX0; X1 = NX1; X2 = NX2; X3 = NX3; X4 = NX4;
            Y0 = NY0; Y1 = NY1; Y2 = NY2; Y3 = NY3; Y4 = NY4;
            i = inext;
        }
    }
    if (i < cnt) eval_single_at(A, lst[i], Bq, W, p0, p1, p2);
}

__global__ void prep_kernel(const int* __restrict__ index,
                            const float* __restrict__ data,
                            const float* __restrict__ wf0, const float* __restrict__ bf0,
                            const float* __restrict__ sw0, const float* __restrict__ sb0,
                            const float* __restrict__ wf1, const float* __restrict__ bf1,
                            const float* __restrict__ wf2, const float* __restrict__ bf2,
                            const float* __restrict__ wf3, const float* __restrict__ bf3,
                            const float* __restrict__ sw1, const float* __restrict__ sb1,
                            const float* __restrict__ sw2, const float* __restrict__ sb2,
                            const float* __restrict__ sw3, const float* __restrict__ sb3,
                            float* __restrict__ wsp) {
    int i = blockIdx.x * blockDim.x + threadIdx.x;
    if (i < NROWS) {
        float d[7], cen[7];
#pragma unroll
        for (int c = 0; c < 7; ++c) d[c] = data[i * 7 + c];
        int ci = index[i];
#pragma unroll
        for (int c = 0; c < 7; ++c) cen[c] = data[ci * 7 + c];
#pragma unroll
        for (int j = 0; j < 18; ++j) {
            float af = 0.f;
#pragma unroll
            for (int c = 0; c < 7; ++c) af += d[c] * wf0[c * 18 + j];
            float as = d[0] * sw0[0 * 18 + j] + d[1] * sw0[1 * 18 + j] + d[2] * sw0[2 * 18 + j];
            float bf = bf0[j], bs = sb0[j];
#pragma unroll
            for (int c = 0; c < 3; ++c) bf -= cen[c] * wf0[c * 18 + j];
#pragma unroll
            for (int c = 0; c < 4; ++c) bf += cen[3 + c] * wf0[(7 + c) * 18 + j];
#pragma unroll
            for (int c = 0; c < 3; ++c) bs -= cen[c] * sw0[c * 18 + j];
#pragma unroll
            for (int c = 0; c < 4; ++c) bs += cen[3 + c] * sw0[(3 + c) * 18 + j];
            wsp[OFF_AF + i * 20 + j] = af * TANH_K;
            wsp[OFF_AS + i * 20 + j] = as * TANH_K;
            wsp[OFF_BF + i * 20 + j] = bf * TANH_K;
            wsp[OFF_BS + i * 20 + j] = bs * TANH_K;
        }
        wsp[OFF_AF + i * 20 + 18] = 0.f; wsp[OFF_AF + i * 20 + 19] = 0.f;
        wsp[OFF_AS + i * 20 + 18] = 0.f; wsp[OFF_AS + i * 20 + 19] = 0.f;
        wsp[OFF_BF + i * 20 + 18] = 0.f; wsp[OFF_BF + i * 20 + 19] = 0.f;
        wsp[OFF_BS + i * 20 + 18] = 0.f; wsp[OFF_BS + i * 20 + 19] = 0.f;
    }
    if (blockIdx.x == 0) {
        int t = threadIdx.x;
        float* wp = wsp + OFF_WP;
        for (int k = t; k < 162; k += 256) wp[WP_W1 + k] = wf1[k] * TANH_K;
        for (int k = t; k < 9;   k += 256) wp[WP_B1 + k] = bf1[k] * TANH_K;
        for (int k = t; k < 54;  k += 256) wp[WP_W2 + k] = wf2[k] * TANH_K;
        for (int k = t; k < 6;   k += 256) wp[WP_B2 + k] = bf2[k] * TANH_K;
        for (int k = t; k < 18;  k += 256) wp[WP_W3 + k] = wf3[k];
        for (int k = t; k < 3;   k += 256) wp[WP_B3 + k] = bf3[k];
        for (int k = t; k < 162; k += 256) wp[WP_SOLID + WP_W1 + k] = sw1[k] * TANH_K;
        for (int k = t; k < 9;   k += 256) wp[WP_SOLID + WP_B1 + k] = sb1[k] * TANH_K;
        for (int k = t; k < 54;  k += 256) wp[WP_SOLID + WP_W2 + k] = sw2[k] * TANH_K;
        for (int k = t; k < 6;   k += 256) wp[WP_SOLID + WP_B2 + k] = sb2[k] * TANH_K;
        for (int k = t; k < 18;  k += 256) wp[WP_SOLID + WP_W3 + k] = sw3[k];
        for (int k = t; k < 3;   k += 256) wp[WP_SOLID + WP_B3 + k] = sb3[k];
    }
}

__global__ __launch_bounds__(256)
void compact_kernel(const int* __restrict__ mask,
                    const float* __restrict__ data,
                    float* __restrict__ wsp) {
    const int lane = threadIdx.x & 63;
    const int n = blockIdx.x * 4 + (threadIdx.x >> 6);
    int* counts_f = (int*)(wsp + OFF_CF);
    int* counts_s = (int*)(wsp + OFF_CS);
    unsigned short* lf = (unsigned short*)(wsp + OFF_LISTS) + (size_t)n * MCOLS;
    unsigned short* ls = lf + LF_CAP;
    const int* mrow = mask + (size_t)n * MCOLS;
    int bf = 0, bs = 0;
    const unsigned long long ltmask = (1ull << lane) - 1ull;
#pragma unroll 1
    for (int it = 0; it < MCOLS / 64; ++it) {
        const int m = it * 64 + lane;
        const int mk = mrow[m];
        const float flag = data[m * 7 + 6];
        const bool af = mk && (flag > 0.f);
        const bool as = mk && (flag < 1.f);
        const unsigned long long balf = __ballot(af);
        const unsigned long long bals = __ballot(as);
        if (af) lf[bf + __popcll(balf & ltmask)] = (unsigned short)m;
        if (as) ls[bs + __popcll(bals & ltmask)] = (unsigned short)m;
        bf += __popcll(balf);
        bs += __popcll(bals);
    }
    if (lane == 0) { counts_f[n] = bf; counts_s[n] = bs; }
}

template <int X2>
__device__ __forceinline__ void main_body(const float* __restrict__ wsp,
                                          float* __restrict__ out) {
    const int n = blockIdx.x;
    const int tid = threadIdx.x;
    __shared__ float red[3][4];
    const float* __restrict__ W  = wsp + OFF_WP;
    const float* __restrict__ Bf = wsp + OFF_BF + n * 20;
    const float* __restrict__ Bs = wsp + OFF_BS + n * 20;
    const int cf = ((const int*)(wsp + OFF_CF))[n];
    const int cs = ((const int*)(wsp + OFF_CS))[n];
    const unsigned short* lf = (const unsigned short*)(wsp + OFF_LISTS) + (size_t)n * MCOLS;
    const unsigned short* ls = lf + LF_CAP;

    float p0 = 0.f, p1 = 0.f, p2 = 0.f;
    if (X2) {
        row_loop_x2(wsp + OFF_AF, lf, cf, Bf, W, tid, p0, p1, p2);
        row_loop_x2(wsp + OFF_AS, ls, cs, Bs, W + WP_SOLID, tid, p0, p1, p2);
    } else {
        row_loop_ilp(wsp + OFF_AF, lf, cf, Bf, W, tid, p0, p1, p2);
        row_loop_ilp(wsp + OFF_AS, ls, cs, Bs, W + WP_SOLID, tid, p0, p1, p2);
    }

#pragma unroll
    for (int off = 32; off > 0; off >>= 1) {
        p0 += __shfl_xor(p0, off, 64);
        p1 += __shfl_xor(p1, off, 64);
        p2 += __shfl_xor(p2, off, 64);
    }
    const int wid = tid >> 6;
    if ((tid & 63) == 0) { red[0][wid] = p0; red[1][wid] = p1; red[2][wid] = p2; }
    __syncthreads();
    if (tid == 0) {
        float a0 = 0.f, a1 = 0.f, a2 = 0.f;
#pragma unroll
        for (int w = 0; w < 4; ++w) { a0 += red[0][w]; a1 += red[1][w]; a2 += red[2][w]; }
        out[n * 3 + 0] = a0; out[n * 3 + 1] = a1; out[n * 3 + 2] = a2;
    }
}

// R15 A/B: dual-eval interleave (experiment, first) vs champion (last, validated).
__global__ __launch_bounds__(256, 4)
void main_x2(const float* __restrict__ wsp, float* __restrict__ out) {
    main_body<1>(wsp, out);
}

__global__ __launch_bounds__(256, 4)
void main_ilp(const float* __restrict__ wsp, float* __restrict__ out) {
    main_body<0>(wsp, out);
}

extern "C" void kernel_launch(void* const* d_in, const int* in_sizes, int n_in,
                              void* d_out, int out_size, void* d_ws, size_t ws_size,
                              hipStream_t stream) {
    const int*   mask  = (const int*)d_in[0];
    const int*   index = (const int*)d_in[1];
    const float* data  = (const float*)d_in[2];
    const float* wf0   = (const float*)d_in[3];
    const float* bf0   = (const float*)d_in[4];
    const float* wf1   = (const float*)d_in[5];
    const float* bf1   = (const float*)d_in[6];
    const float* wf2   = (const float*)d_in[7];
    const float* bf2   = (const float*)d_in[8];
    const float* wf3   = (const float*)d_in[9];
    const float* bf3   = (const float*)d_in[10];
    const float* sw0   = (const float*)d_in[11];
    const float* sb0   = (const float*)d_in[12];
    const float* sw1   = (const float*)d_in[13];
    const float* sb1   = (const float*)d_in[14];
    const float* sw2   = (const float*)d_in[15];
    const float* sb2   = (const float*)d_in[16];
    const float* sw3   = (const float*)d_in[17];
    const float* sb3   = (const float*)d_in[18];
    float* wsp = (float*)d_ws;
    float* out = (float*)d_out;

    prep_kernel<<<dim3(8), dim3(256), 0, stream>>>(
        index, data, wf0, bf0, sw0, sb0, wf1, bf1, wf2, bf2, wf3, bf3,
        sw1, sb1, sw2, sb2, sw3, sb3, wsp);
    compact_kernel<<<dim3(NROWS / 4), dim3(256), 0, stream>>>(mask, data, wsp);
    main_x2<<<dim3(NROWS), dim3(256), 0, stream>>>(wsp, out);
    main_ilp<<<dim3(NROWS), dim3(256), 0, stream>>>(wsp, out);
}